// Round 5
// baseline (318.102 us; speedup 1.0000x reference)
//
#include <hip/hip_runtime.h>

// EGNN, MFMA core + scale-folded SiLU chain, full-residency config.
// B=64, N=128, M=16, L=2. Per wave: one (b,i) row, 8 tiles of 16 edges.
//  Stage A (collapsed to ti/tj/dist): fp32 VALU in C-layout.
//  Stage B (16->16), C (16->64): mfma_f32_16x16x32_bf16, weights=A operand,
//    [hi;lo] bf16 split in K=32 slots (~16-bit weight precision).
//  Stage D (64->1): fp32 dot + wave butterfly reduce.
// SiLU scale-folding: silu inputs carry log2(e); silu' = x'*rcp(1+exp2(-x'));
// factor absorbed by next stage (ln2*log2e=1 -> We2/Wc1 unscaled, biases
// *log2e, Wc2 *ln2). Exact in fp32.
// __launch_bounds__(256,8): VGPR<=64 so all 8 blocks/CU of the 2048-block
// grid are co-resident (block-granular residency: 80 VGPR -> 6+2 split tail
// cost ~= the interleave's ILP gain; 8 waves/SIMD already hides latency).

#define NB 64
#define NN 128
#define LOG2E 1.4426950408889634f
#define LN2f  0.6931471805599453f

typedef __attribute__((ext_vector_type(8))) short short8;
typedef __attribute__((ext_vector_type(4))) float floatx4;

__device__ __forceinline__ unsigned short f2bf(float x) {
    unsigned u = __float_as_uint(x);
    return (unsigned short)((u + 0x7FFFu + ((u >> 16) & 1u)) >> 16);
}
__device__ __forceinline__ float bf2f(unsigned short b) {
    return __uint_as_float(((unsigned)b) << 16);
}
// pack two f32 -> bf16x2 (round-half-up): 2 adds + 1 v_perm
__device__ __forceinline__ unsigned packbf(float x, float y) {
    unsigned xb = __float_as_uint(x) + 0x8000u;
    unsigned yb = __float_as_uint(y) + 0x8000u;
    return __builtin_amdgcn_perm(yb, xb, 0x07060302u);
}
// input xs = x*log2e; returns silu(x)*log2e
__device__ __forceinline__ float silu_s(float xs) {
    float e = __builtin_amdgcn_exp2f(-xs);
    return xs * __builtin_amdgcn_rcpf(1.0f + e);
}
__device__ __forceinline__ float selu_f(float x) {
    const float alpha = 1.6732632423543772f;
    const float scale = 1.0507009873554805f;
    float neg = alpha * (__expf(x) - 1.0f);
    return scale * (x > 0.0f ? x : neg);
}

// ---- prep: collapsed/scaled We1 coeffs, bf16 hi/lo frags, scaled biases ----
// ws float layout per layer (stride 2048 floats):
//  [0,16)A' [16,32)B' [32,48)C' [48,64)D'   (all *log2e, D' includes be1)
//  [64,320) wB frags   [320,1344) wC frags
//  [1344,1360) be2*log2e  [1360,1424) bc1*log2e  [1424,1488) Wc2*ln2
__global__ __launch_bounds__(128) void egnn_prep(
    const float* __restrict__ We1, const float* __restrict__ be1,
    const float* __restrict__ We2, const float* __restrict__ be2,
    const float* __restrict__ Wc1, const float* __restrict__ bc1,
    const float* __restrict__ Wc2,
    float* __restrict__ prep)
{
    const int layer = threadIdx.x >> 6;
    const int l = threadIdx.x & 63;
    const int q = l >> 4, em = l & 15;
    const float* We1l = We1 + layer * 128;
    const float* be1l = be1 + layer * 16;
    const float* We2l = We2 + layer * 256;
    const float* be2l = be2 + layer * 16;
    const float* Wc1l = Wc1 + layer * 1024;
    const float* bc1l = bc1 + layer * 64;
    const float* Wc2l = Wc2 + layer * 64;
    float* P = prep + layer * 2048;

    if (l < 16) {
        P[l]      = (We1l[l] + We1l[16 + l] + We1l[32 + l]) * LOG2E;
        P[16 + l] = (We1l[48 + l] + We1l[64 + l] + We1l[80 + l]) * LOG2E;
        P[32 + l] = We1l[96 + l] * LOG2E;
        P[48 + l] = (We1l[112 + l] + be1l[l]) * LOG2E;
        P[1344 + l] = be2l[l] * LOG2E;
    }
    P[1360 + l] = bc1l[l] * LOG2E;
    P[1424 + l] = Wc2l[l] * LN2f;

    // wB: A[m=em][k=q*8+j], k<16 -> hi(We2[k][m]), else lo(We2[k-16][m])
    {
        unsigned wb[4];
#pragma unroll
        for (int d = 0; d < 4; ++d) {
            unsigned short sv[2];
#pragma unroll
            for (int e = 0; e < 2; ++e) {
                int k = q * 8 + 2 * d + e;
                float w = We2l[(k & 15) * 16 + em];
                unsigned short hv = f2bf(w);
                unsigned short lv = f2bf(w - bf2f(hv));
                sv[e] = (k < 16) ? hv : lv;
            }
            wb[d] = (unsigned)sv[0] | ((unsigned)sv[1] << 16);
        }
        *(uint4*)((unsigned*)(P + 64) + l * 4) = make_uint4(wb[0], wb[1], wb[2], wb[3]);
    }
    // wC: 4 fragments of 16 out-channels each
#pragma unroll
    for (int f = 0; f < 4; ++f) {
        unsigned wc[4];
#pragma unroll
        for (int d = 0; d < 4; ++d) {
            unsigned short sv[2];
#pragma unroll
            for (int e = 0; e < 2; ++e) {
                int k = q * 8 + 2 * d + e;
                float w = Wc1l[(k & 15) * 64 + 16 * f + em];
                unsigned short hv = f2bf(w);
                unsigned short lv = f2bf(w - bf2f(hv));
                sv[e] = (k < 16) ? hv : lv;
            }
            wc[d] = (unsigned)sv[0] | ((unsigned)sv[1] << 16);
        }
        *(uint4*)((unsigned*)(P + 320) + l * 16 + f * 4) = make_uint4(wc[0], wc[1], wc[2], wc[3]);
    }
}

template <bool DO_HEAD>
__global__ __launch_bounds__(256, 8) void egnn_layer(
    const float* __restrict__ t,
    const float* __restrict__ coors_in,
    const float* __restrict__ vel_in,
    const float* __restrict__ prep,
    const float* __restrict__ bc2,
    const float* __restrict__ Wv,  const float* __restrict__ bv,
    const float* __restrict__ Wconv1, const float* __restrict__ bconv1,
    const float* __restrict__ Wconv2, const float* __restrict__ bconv2,
    int layer,
    float* __restrict__ coors_out, float* __restrict__ vel_out,
    float* __restrict__ out)
{
    const int l   = threadIdx.x & 63;
    const int wvi = threadIdx.x >> 6;
    const int row = blockIdx.x * 4 + wvi;     // b*128 + i
    const int b   = row >> 7;
    const int i   = row & 127;
    const int q   = l >> 4;                   // quad 0..3
    const int em  = l & 15;                   // edge-in-tile / out-row group

    const float* P = prep + layer * 2048;
    const float  wv_s = Wv[layer * 3 + 0] + Wv[layer * 3 + 1] + Wv[layer * 3 + 2];
    const float  bvl  = bv[layer];

    // prologue: per-lane fragment loads (L2-hot prep)
    const float4 a4 = *(const float4*)(P + 0  + q * 4);
    const float4 b4 = *(const float4*)(P + 16 + q * 4);
    const float4 c4 = *(const float4*)(P + 32 + q * 4);
    const float4 d4 = *(const float4*)(P + 48 + q * 4);
    const short8 wB = __builtin_bit_cast(short8, *(const uint4*)((const unsigned*)(P + 64) + l * 4));
    short8 wC[4];
#pragma unroll
    for (int f = 0; f < 4; ++f)
        wC[f] = __builtin_bit_cast(short8, *(const uint4*)((const unsigned*)(P + 320) + l * 16 + f * 4));
    const floatx4 biasB = __builtin_bit_cast(floatx4, *(const float4*)(P + 1344 + q * 4));
    floatx4 biasC[4];
    float4 w2[4];
#pragma unroll
    for (int f = 0; f < 4; ++f) {
        biasC[f] = __builtin_bit_cast(floatx4, *(const float4*)(P + 1360 + f * 16 + q * 4));
        w2[f]    = *(const float4*)(P + 1424 + f * 16 + q * 4);
    }
    const float bc2q = (q == 0) ? bc2[layer] : 0.0f;

    const float* tptr = t + b * NN;
    const float ti = tptr[i];
    const float2* cin = (const float2*)coors_in + b * NN;
    const float2 ci = cin[i];

    // shuffle sources for C-layout -> B-operand transform (loop-invariant)
    const int sA = em + ((q & 1) << 5);
    const int sB = sA + 16;

    float ax = 0.0f, ay = 0.0f;

    // prefetch tile 0
    float tj_n = tptr[em];
    float2 cj_n = cin[em];

#pragma unroll 1
    for (int tt = 0; tt < 8; ++tt) {
        const float tj = tj_n;
        const float2 cj = cj_n;
        if (tt < 7) {                 // prefetch next tile (L1/L2-hot)
            const int jn = (tt + 1) * 16 + em;
            tj_n = tptr[jn];
            cj_n = cin[jn];
        }
        const float rx = ci.x - cj.x, ry = ci.y - cj.y;
        const float dist = fmaf(rx, rx, ry * ry);

        // Stage A: fp32, result in C-layout (rows 4q+r, col em), *log2e
        float s0 = fmaf(ti, a4.x, fmaf(tj, b4.x, fmaf(dist, c4.x, d4.x)));
        float s1 = fmaf(ti, a4.y, fmaf(tj, b4.y, fmaf(dist, c4.y, d4.y)));
        float s2 = fmaf(ti, a4.z, fmaf(tj, b4.z, fmaf(dist, c4.z, d4.z)));
        float s3 = fmaf(ti, a4.w, fmaf(tj, b4.w, fmaf(dist, c4.w, d4.w)));
        unsigned P0 = packbf(silu_s(s0), silu_s(s1));
        unsigned P1 = packbf(silu_s(s2), silu_s(s3));
        uint4 tb;
        tb.x = (unsigned)__shfl((int)P0, sA, 64);
        tb.y = (unsigned)__shfl((int)P1, sA, 64);
        tb.z = (unsigned)__shfl((int)P0, sB, 64);
        tb.w = (unsigned)__shfl((int)P1, sB, 64);

        // Stage B: m = silu(W2 . e1 + b2); sm = silu(m)
        floatx4 accB = __builtin_amdgcn_mfma_f32_16x16x32_bf16(
            wB, __builtin_bit_cast(short8, tb), biasB, 0, 0, 0);
        unsigned Q0 = packbf(silu_s(silu_s(accB[0])), silu_s(silu_s(accB[1])));
        unsigned Q1 = packbf(silu_s(silu_s(accB[2])), silu_s(silu_s(accB[3])));
        uint4 tc;
        tc.x = (unsigned)__shfl((int)Q0, sA, 64);
        tc.y = (unsigned)__shfl((int)Q1, sA, 64);
        tc.z = (unsigned)__shfl((int)Q0, sB, 64);
        tc.w = (unsigned)__shfl((int)Q1, sB, 64);
        const short8 bC = __builtin_bit_cast(short8, tc);

        // Stage C: h = silu(Wc1 . sm + bc1), 64 channels in 4 fragments
        floatx4 h0 = __builtin_amdgcn_mfma_f32_16x16x32_bf16(wC[0], bC, biasC[0], 0, 0, 0);
        floatx4 h1 = __builtin_amdgcn_mfma_f32_16x16x32_bf16(wC[1], bC, biasC[1], 0, 0, 0);
        floatx4 h2 = __builtin_amdgcn_mfma_f32_16x16x32_bf16(wC[2], bC, biasC[2], 0, 0, 0);
        floatx4 h3 = __builtin_amdgcn_mfma_f32_16x16x32_bf16(wC[3], bC, biasC[3], 0, 0, 0);

        // Stage D: per-lane partial of w_ij over 16 of 64 channels
        float wp = bc2q;
#pragma unroll
        for (int r = 0; r < 4; ++r) wp = fmaf(silu_s(h0[r]), ((const float*)&w2[0])[r], wp);
#pragma unroll
        for (int r = 0; r < 4; ++r) wp = fmaf(silu_s(h1[r]), ((const float*)&w2[1])[r], wp);
#pragma unroll
        for (int r = 0; r < 4; ++r) wp = fmaf(silu_s(h2[r]), ((const float*)&w2[2])[r], wp);
#pragma unroll
        for (int r = 0; r < 4; ++r) wp = fmaf(silu_s(h3[r]), ((const float*)&w2[3])[r], wp);

        ax = fmaf(wp, rx, ax);
        ay = fmaf(wp, ry, ay);
    }

    // sum agg over all 64 lanes (quads hold channel-partials, em holds edges)
#pragma unroll
    for (int m = 32; m >= 1; m >>= 1) {
        ax += __shfl_xor(ax, m, 64);
        ay += __shfl_xor(ay, m, 64);
    }

    // node update, computed uniformly on all lanes (ax/ay now uniform)
    const float2 vi = ((const float2*)vel_in + b * NN)[i];
    const float phi = fmaf(ti, wv_s, bvl);
    float vx = fmaf(phi, vi.x, ax);
    float vy = fmaf(phi, vi.y, ay);
    float cx = selu_f(ci.x + vx);
    float cy = selu_f(ci.y + vy);
    vx = selu_f(vx); vy = selu_f(vy);

    if (!DO_HEAD) {
        if (l == 0) {
            ((float2*)coors_out + b * NN)[i] = make_float2(cx, cy);
            ((float2*)vel_out + b * NN)[i]   = make_float2(vx, vy);
        }
    } else {
        // conv head distributed: channel c = lane&31, butterfly-reduce 4 outs
        const float x0 = selu_f(cx), x1 = selu_f(cy);
        const float x2 = selu_f(vx), x3 = selu_f(vy);
        const int c = l & 31;
        const float4 w1 = *(const float4*)(Wconv1 + c * 4);
        const float xc = selu_f(bconv1[c] + fmaf(x0, w1.x, fmaf(x1, w1.y, fmaf(x2, w1.z, x3 * w1.w))));
        float y0 = xc * Wconv2[c];
        float y1 = xc * Wconv2[32 + c];
        float y2 = xc * Wconv2[64 + c];
        float y3 = xc * Wconv2[96 + c];
#pragma unroll
        for (int m = 16; m >= 1; m >>= 1) {
            y0 += __shfl_xor(y0, m, 64);
            y1 += __shfl_xor(y1, m, 64);
            y2 += __shfl_xor(y2, m, 64);
            y3 += __shfl_xor(y3, m, 64);
        }
        if (l == 0) {
            const int idx = (b * NN + i) * 2;
            *(float2*)(out + idx) = make_float2(y0 + bconv2[0], y1 + bconv2[1]);
            *(float2*)(out + NB * NN * 2 + idx) = make_float2(y2 + bconv2[2], y3 + bconv2[3]);
        }
    }
}

extern "C" void kernel_launch(void* const* d_in, const int* in_sizes, int n_in,
                              void* d_out, int out_size, void* d_ws, size_t ws_size,
                              hipStream_t stream) {
    const float* t      = (const float*)d_in[0];
    const float* coors  = (const float*)d_in[1];
    const float* vel    = (const float*)d_in[2];
    const float* We1    = (const float*)d_in[3];
    const float* be1    = (const float*)d_in[4];
    const float* We2    = (const float*)d_in[5];
    const float* be2    = (const float*)d_in[6];
    const float* Wc1    = (const float*)d_in[7];
    const float* bc1    = (const float*)d_in[8];
    const float* Wc2    = (const float*)d_in[9];
    const float* bc2    = (const float*)d_in[10];
    const float* Wv     = (const float*)d_in[11];
    const float* bv     = (const float*)d_in[12];
    const float* Wconv1 = (const float*)d_in[13];
    const float* bconv1 = (const float*)d_in[14];
    const float* Wconv2 = (const float*)d_in[15];
    const float* bconv2 = (const float*)d_in[16];
    float* out = (float*)d_out;

    float* ws     = (float*)d_ws;
    float* coors1 = ws;                     // B*N*2 floats
    float* vel1   = ws + NB * NN * 2;       // B*N*2 floats
    float* prep   = ws + 2 * NB * NN * 2;   // 2 layers x 2048 floats

    egnn_prep<<<dim3(1), dim3(128), 0, stream>>>(We1, be1, We2, be2, Wc1, bc1, Wc2, prep);

    const dim3 grid(2048), block(256);      // 8192 rows, 1 wave per row

    egnn_layer<false><<<grid, block, 0, stream>>>(
        t, coors, vel, prep, bc2, Wv, bv,
        Wconv1, bconv1, Wconv2, bconv2, 0, coors1, vel1, nullptr);

    egnn_layer<true><<<grid, block, 0, stream>>>(
        t, coors1, vel1, prep, bc2, Wv, bv,
        Wconv1, bconv1, Wconv2, bconv2, 1, nullptr, nullptr, out);
}

// Round 7
// 158.237 us; speedup vs baseline: 2.0103x; 2.0103x over previous
//
#include <hip/hip_runtime.h>

// EGNN, MFMA core + scale-folded SiLU, 2 dispatches (prep fused into each
// layer kernel as per-block LDS prep). B=64, N=128, M=16, L=2.
// Per wave: one (b,i) row, 8 tiles of 16 edges.
//  Stage A (collapsed to ti/tj/dist): fp32 VALU in MFMA C-layout.
//  Stage B (16->16), C (16->64): mfma_f32_16x16x32_bf16, weights=A operand,
//    [hi;lo] bf16 split in K=32 slots (~16-bit weight precision).
//  Stage D (64->1): fp32 dot + wave butterfly reduce.
// SiLU scale-folding: silu inputs carry log2(e); silu' = x'*rcp(1+exp2(-x'));
// factor absorbed downstream (ln2*log2e=1 -> We2/Wc1 unscaled, biases *log2e,
// Wc2 *ln2). Exact in fp32.
// NOTE r5: __launch_bounds__(256,8) forced 32 VGPR -> 300MB of scratch spill
// traffic, 3x slower. NOTE r6: hipLaunchCooperativeKernel(1024 blocks) failed
// silently (co-residency precondition). Plain (256) bounds; 2048-block grid.

#define NB 64
#define NN 128
#define LOG2E 1.4426950408889634f
#define LN2f  0.6931471805599453f

typedef __attribute__((ext_vector_type(8))) short short8;
typedef __attribute__((ext_vector_type(4))) float floatx4;

__device__ __forceinline__ unsigned short f2bf(float x) {
    unsigned u = __float_as_uint(x);
    return (unsigned short)((u + 0x7FFFu + ((u >> 16) & 1u)) >> 16);
}
__device__ __forceinline__ float bf2f(unsigned short b) {
    return __uint_as_float(((unsigned)b) << 16);
}
// pack two f32 -> bf16x2 (round-half-up): 2 adds + 1 v_perm
__device__ __forceinline__ unsigned packbf(float x, float y) {
    unsigned xb = __float_as_uint(x) + 0x8000u;
    unsigned yb = __float_as_uint(y) + 0x8000u;
    return __builtin_amdgcn_perm(yb, xb, 0x07060302u);
}
// input xs = x*log2e; returns silu(x)*log2e
__device__ __forceinline__ float silu_s(float xs) {
    float e = __builtin_amdgcn_exp2f(-xs);
    return xs * __builtin_amdgcn_rcpf(1.0f + e);
}
__device__ __forceinline__ float selu_f(float x) {
    const float alpha = 1.6732632423543772f;
    const float scale = 1.0507009873554805f;
    float neg = alpha * (__expf(x) - 1.0f);
    return scale * (x > 0.0f ? x : neg);
}

// LDS layout (1536 floats = 6 KB):
//  [0,16)A' [16,32)B' [32,48)C' [48,64)D'   (all *log2e, D' includes be1)
//  [64,320) wB frags (4 uints/lane)  [320,1344) wC frags (16 uints/lane)
//  [1344,1360) be2*log2e  [1360,1424) bc1*log2e  [1424,1488) Wc2*ln2
template <bool DO_HEAD>
__global__ __launch_bounds__(256) void egnn_layer(
    const float* __restrict__ t,
    const float* __restrict__ coors_in,
    const float* __restrict__ vel_in,
    const float* __restrict__ We1, const float* __restrict__ be1,
    const float* __restrict__ We2, const float* __restrict__ be2,
    const float* __restrict__ Wc1, const float* __restrict__ bc1,
    const float* __restrict__ Wc2, const float* __restrict__ bc2,
    const float* __restrict__ Wv,  const float* __restrict__ bv,
    const float* __restrict__ Wconv1, const float* __restrict__ bconv1,
    const float* __restrict__ Wconv2, const float* __restrict__ bconv2,
    int layer,
    float* __restrict__ coors_out, float* __restrict__ vel_out,
    float* __restrict__ out)
{
    __shared__ float P[1536];

    // ---- per-block prep into LDS (one wave) ----
    if (threadIdx.x < 64) {
        const int pl = threadIdx.x;
        const int pq = pl >> 4, pem = pl & 15;
        const float* We1l = We1 + layer * 128;
        const float* be1l = be1 + layer * 16;
        const float* We2l = We2 + layer * 256;
        const float* be2l = be2 + layer * 16;
        const float* Wc1l = Wc1 + layer * 1024;
        const float* bc1l = bc1 + layer * 64;
        const float* Wc2l = Wc2 + layer * 64;

        if (pl < 16) {
            P[pl]      = (We1l[pl] + We1l[16 + pl] + We1l[32 + pl]) * LOG2E;
            P[16 + pl] = (We1l[48 + pl] + We1l[64 + pl] + We1l[80 + pl]) * LOG2E;
            P[32 + pl] = We1l[96 + pl] * LOG2E;
            P[48 + pl] = (We1l[112 + pl] + be1l[pl]) * LOG2E;
            P[1344 + pl] = be2l[pl] * LOG2E;
        }
        P[1360 + pl] = bc1l[pl] * LOG2E;
        P[1424 + pl] = Wc2l[pl] * LN2f;

        // wB: A[m=pem][k=pq*8+j], k<16 -> hi(We2[k][m]), else lo(We2[k-16][m])
        {
            unsigned wb[4];
#pragma unroll
            for (int d = 0; d < 4; ++d) {
                unsigned short sv[2];
#pragma unroll
                for (int e = 0; e < 2; ++e) {
                    int k = pq * 8 + 2 * d + e;
                    float w = We2l[(k & 15) * 16 + pem];
                    unsigned short hv = f2bf(w);
                    unsigned short lv = f2bf(w - bf2f(hv));
                    sv[e] = (k < 16) ? hv : lv;
                }
                wb[d] = (unsigned)sv[0] | ((unsigned)sv[1] << 16);
            }
            *(uint4*)((unsigned*)(P + 64) + pl * 4) = make_uint4(wb[0], wb[1], wb[2], wb[3]);
        }
        // wC: 4 fragments of 16 out-channels each
#pragma unroll
        for (int f = 0; f < 4; ++f) {
            unsigned wc[4];
#pragma unroll
            for (int d = 0; d < 4; ++d) {
                unsigned short sv[2];
#pragma unroll
                for (int e = 0; e < 2; ++e) {
                    int k = pq * 8 + 2 * d + e;
                    float w = Wc1l[(k & 15) * 64 + 16 * f + pem];
                    unsigned short hv = f2bf(w);
                    unsigned short lv = f2bf(w - bf2f(hv));
                    sv[e] = (k < 16) ? hv : lv;
                }
                wc[d] = (unsigned)sv[0] | ((unsigned)sv[1] << 16);
            }
            *(uint4*)((unsigned*)(P + 320) + pl * 16 + f * 4) = make_uint4(wc[0], wc[1], wc[2], wc[3]);
        }
    }
    __syncthreads();

    const int l   = threadIdx.x & 63;
    const int wvi = threadIdx.x >> 6;
    const int row = blockIdx.x * 4 + wvi;     // b*128 + i
    const int b   = row >> 7;
    const int i   = row & 127;
    const int q   = l >> 4;                   // quad 0..3
    const int em  = l & 15;                   // edge-in-tile / out-row group

    // per-lane fragment loads from LDS
    const float4 a4 = *(const float4*)(P + 0  + q * 4);
    const float4 b4 = *(const float4*)(P + 16 + q * 4);
    const float4 c4 = *(const float4*)(P + 32 + q * 4);
    const float4 d4 = *(const float4*)(P + 48 + q * 4);
    const short8 wB = __builtin_bit_cast(short8, *(const uint4*)((const unsigned*)(P + 64) + l * 4));
    short8 wC[4];
    floatx4 biasC[4];
#pragma unroll
    for (int f = 0; f < 4; ++f) {
        wC[f] = __builtin_bit_cast(short8, *(const uint4*)((const unsigned*)(P + 320) + l * 16 + f * 4));
        biasC[f] = __builtin_bit_cast(floatx4, *(const float4*)(P + 1360 + f * 16 + q * 4));
    }
    const floatx4 biasB = __builtin_bit_cast(floatx4, *(const float4*)(P + 1344 + q * 4));
    const float bc2q = (q == 0) ? bc2[layer] : 0.0f;
    const float wv_s = Wv[layer * 3 + 0] + Wv[layer * 3 + 1] + Wv[layer * 3 + 2];
    const float bvl  = bv[layer];

    const float* tptr = t + b * NN;
    const float ti = tptr[i];
    const float2* cin = (const float2*)coors_in + b * NN;
    const float2 ci = cin[i];

    // shuffle sources for C-layout -> B-operand transform (loop-invariant)
    const int sA = em + ((q & 1) << 5);
    const int sB = sA + 16;

    float ax = 0.0f, ay = 0.0f;

    // prefetch tile 0
    float tj_n = tptr[em];
    float2 cj_n = cin[em];

#pragma unroll 1
    for (int tt = 0; tt < 8; ++tt) {
        const float tj = tj_n;
        const float2 cj = cj_n;
        if (tt < 7) {                 // prefetch next tile (L1/L2-hot)
            const int jn = (tt + 1) * 16 + em;
            tj_n = tptr[jn];
            cj_n = cin[jn];
        }
        const float rx = ci.x - cj.x, ry = ci.y - cj.y;
        const float dist = fmaf(rx, rx, ry * ry);

        // Stage A: fp32, result in C-layout (rows 4q+r, col em), *log2e
        float s0 = fmaf(ti, a4.x, fmaf(tj, b4.x, fmaf(dist, c4.x, d4.x)));
        float s1 = fmaf(ti, a4.y, fmaf(tj, b4.y, fmaf(dist, c4.y, d4.y)));
        float s2 = fmaf(ti, a4.z, fmaf(tj, b4.z, fmaf(dist, c4.z, d4.z)));
        float s3 = fmaf(ti, a4.w, fmaf(tj, b4.w, fmaf(dist, c4.w, d4.w)));
        unsigned P0 = packbf(silu_s(s0), silu_s(s1));
        unsigned P1 = packbf(silu_s(s2), silu_s(s3));
        uint4 tb;
        tb.x = (unsigned)__shfl((int)P0, sA, 64);
        tb.y = (unsigned)__shfl((int)P1, sA, 64);
        tb.z = (unsigned)__shfl((int)P0, sB, 64);
        tb.w = (unsigned)__shfl((int)P1, sB, 64);

        // Stage B: m = silu(W2 . e1 + b2); sm = silu(m)
        floatx4 accB = __builtin_amdgcn_mfma_f32_16x16x32_bf16(
            wB, __builtin_bit_cast(short8, tb), biasB, 0, 0, 0);
        unsigned Q0 = packbf(silu_s(silu_s(accB[0])), silu_s(silu_s(accB[1])));
        unsigned Q1 = packbf(silu_s(silu_s(accB[2])), silu_s(silu_s(accB[3])));
        uint4 tc;
        tc.x = (unsigned)__shfl((int)Q0, sA, 64);
        tc.y = (unsigned)__shfl((int)Q1, sA, 64);
        tc.z = (unsigned)__shfl((int)Q0, sB, 64);
        tc.w = (unsigned)__shfl((int)Q1, sB, 64);
        const short8 bC = __builtin_bit_cast(short8, tc);

        // Stage C: h = silu(Wc1 . sm + bc1), 64 channels in 4 fragments
        floatx4 h0 = __builtin_amdgcn_mfma_f32_16x16x32_bf16(wC[0], bC, biasC[0], 0, 0, 0);
        floatx4 h1 = __builtin_amdgcn_mfma_f32_16x16x32_bf16(wC[1], bC, biasC[1], 0, 0, 0);
        floatx4 h2 = __builtin_amdgcn_mfma_f32_16x16x32_bf16(wC[2], bC, biasC[2], 0, 0, 0);
        floatx4 h3 = __builtin_amdgcn_mfma_f32_16x16x32_bf16(wC[3], bC, biasC[3], 0, 0, 0);

        // Stage D: per-lane partial of w_ij over 16 of 64 channels
        // (w2 read from LDS per use to keep persistent VGPRs low)
        float wp = bc2q;
#pragma unroll
        for (int f = 0; f < 4; ++f) {
            const float4 w2f = *(const float4*)(P + 1424 + f * 16 + q * 4);
            const floatx4 hf = (f == 0) ? h0 : (f == 1) ? h1 : (f == 2) ? h2 : h3;
            wp = fmaf(silu_s(hf[0]), w2f.x, wp);
            wp = fmaf(silu_s(hf[1]), w2f.y, wp);
            wp = fmaf(silu_s(hf[2]), w2f.z, wp);
            wp = fmaf(silu_s(hf[3]), w2f.w, wp);
        }

        ax = fmaf(wp, rx, ax);
        ay = fmaf(wp, ry, ay);
    }

    // sum agg over all 64 lanes (quads hold channel-partials, em holds edges)
#pragma unroll
    for (int m = 32; m >= 1; m >>= 1) {
        ax += __shfl_xor(ax, m, 64);
        ay += __shfl_xor(ay, m, 64);
    }

    // node update, computed uniformly on all lanes (ax/ay now uniform)
    const float2 vi2 = ((const float2*)vel_in + b * NN)[i];
    const float phi = fmaf(ti, wv_s, bvl);
    float vx = fmaf(phi, vi2.x, ax);
    float vy = fmaf(phi, vi2.y, ay);
    float cx = selu_f(ci.x + vx);
    float cy = selu_f(ci.y + vy);
    vx = selu_f(vx); vy = selu_f(vy);

    if (!DO_HEAD) {
        if (l == 0) {
            ((float2*)coors_out + b * NN)[i] = make_float2(cx, cy);
            ((float2*)vel_out + b * NN)[i]   = make_float2(vx, vy);
        }
    } else {
        // conv head distributed: channel c = lane&31, butterfly-reduce 4 outs
        const float x0 = selu_f(cx), x1 = selu_f(cy);
        const float x2 = selu_f(vx), x3 = selu_f(vy);
        const int c = l & 31;
        const float4 w1 = *(const float4*)(Wconv1 + c * 4);
        const float xc = selu_f(bconv1[c] + fmaf(x0, w1.x, fmaf(x1, w1.y, fmaf(x2, w1.z, x3 * w1.w))));
        float y0 = xc * Wconv2[c];
        float y1 = xc * Wconv2[32 + c];
        float y2 = xc * Wconv2[64 + c];
        float y3 = xc * Wconv2[96 + c];
#pragma unroll
        for (int m = 16; m >= 1; m >>= 1) {
            y0 += __shfl_xor(y0, m, 64);
            y1 += __shfl_xor(y1, m, 64);
            y2 += __shfl_xor(y2, m, 64);
            y3 += __shfl_xor(y3, m, 64);
        }
        if (l == 0) {
            const int idx = (b * NN + i) * 2;
            *(float2*)(out + idx) = make_float2(y0 + bconv2[0], y1 + bconv2[1]);
            *(float2*)(out + NB * NN * 2 + idx) = make_float2(y2 + bconv2[2], y3 + bconv2[3]);
        }
    }
}

extern "C" void kernel_launch(void* const* d_in, const int* in_sizes, int n_in,
                              void* d_out, int out_size, void* d_ws, size_t ws_size,
                              hipStream_t stream) {
    const float* t      = (const float*)d_in[0];
    const float* coors  = (const float*)d_in[1];
    const float* vel    = (const float*)d_in[2];
    const float* We1    = (const float*)d_in[3];
    const float* be1    = (const float*)d_in[4];
    const float* We2    = (const float*)d_in[5];
    const float* be2    = (const float*)d_in[6];
    const float* Wc1    = (const float*)d_in[7];
    const float* bc1    = (const float*)d_in[8];
    const float* Wc2    = (const float*)d_in[9];
    const float* bc2    = (const float*)d_in[10];
    const float* Wv     = (const float*)d_in[11];
    const float* bv     = (const float*)d_in[12];
    const float* Wconv1 = (const float*)d_in[13];
    const float* bconv1 = (const float*)d_in[14];
    const float* Wconv2 = (const float*)d_in[15];
    const float* bconv2 = (const float*)d_in[16];
    float* out = (float*)d_out;

    float* ws     = (float*)d_ws;
    float* coors1 = ws;                     // B*N*2 floats
    float* vel1   = ws + NB * NN * 2;       // B*N*2 floats

    const dim3 grid(2048), block(256);      // 8192 rows, 1 wave per row

    egnn_layer<false><<<grid, block, 0, stream>>>(
        t, coors, vel, We1, be1, We2, be2, Wc1, bc1, Wc2, bc2, Wv, bv,
        Wconv1, bconv1, Wconv2, bconv2, 0, coors1, vel1, nullptr);

    egnn_layer<true><<<grid, block, 0, stream>>>(
        t, coors1, vel1, We1, be1, We2, be2, Wc1, bc1, Wc2, bc2, Wv, bv,
        Wconv1, bconv1, Wconv2, bconv2, 1, nullptr, nullptr, out);
}

// Round 8
// 157.516 us; speedup vs baseline: 2.0195x; 1.0046x over previous
//
#include <hip/hip_runtime.h>

// EGNN, MFMA core + scale-folded SiLU, 2 dispatches (prep fused into each
// layer kernel as per-block LDS prep). B=64, N=128, M=16, L=2.
// Per wave: one (b,i) row, 8 tiles of 16 edges, visited in a per-wave
// rotated order (desyncs the trans-pipe convoy across co-resident waves).
//  Stage A (collapsed to ti/tj/dist): fp32 VALU in MFMA C-layout.
//  Stage B (16->16), C (16->64): mfma_f32_16x16x32_bf16, weights=A operand,
//    [hi;lo] bf16 split in K=32 slots (~16-bit weight precision).
//  Stage D (64->1): fp32 dot (weights in VGPRs) + wave butterfly reduce.
// SiLU scale-folding: silu inputs carry log2(e); silu' = x'*rcp(1+exp2(-x'));
// factor absorbed downstream (ln2*log2e=1 -> We2/Wc1 unscaled, biases *log2e,
// Wc2 *ln2). Exact in fp32.
// NOTE r5: __launch_bounds__(256,8) -> 32 VGPR -> 300MB spill traffic, 3x slow.
// NOTE r6: hipLaunchCooperativeKernel failed silently under graph capture.
// NOTE r7: wall-time overhead (~70us) is fixed, not per-dispatch.

#define NB 64
#define NN 128
#define LOG2E 1.4426950408889634f
#define LN2f  0.6931471805599453f

typedef __attribute__((ext_vector_type(8))) short short8;
typedef __attribute__((ext_vector_type(4))) float floatx4;

__device__ __forceinline__ unsigned short f2bf(float x) {
    unsigned u = __float_as_uint(x);
    return (unsigned short)((u + 0x7FFFu + ((u >> 16) & 1u)) >> 16);
}
__device__ __forceinline__ float bf2f(unsigned short b) {
    return __uint_as_float(((unsigned)b) << 16);
}
// pack two f32 -> bf16x2 (round-half-up): 2 adds + 1 v_perm
__device__ __forceinline__ unsigned packbf(float x, float y) {
    unsigned xb = __float_as_uint(x) + 0x8000u;
    unsigned yb = __float_as_uint(y) + 0x8000u;
    return __builtin_amdgcn_perm(yb, xb, 0x07060302u);
}
// input xs = x*log2e; returns silu(x)*log2e
__device__ __forceinline__ float silu_s(float xs) {
    float e = __builtin_amdgcn_exp2f(-xs);
    return xs * __builtin_amdgcn_rcpf(1.0f + e);
}
__device__ __forceinline__ float selu_f(float x) {
    const float alpha = 1.6732632423543772f;
    const float scale = 1.0507009873554805f;
    float neg = alpha * (__expf(x) - 1.0f);
    return scale * (x > 0.0f ? x : neg);
}

// LDS layout (1536 floats = 6 KB):
//  [0,16)A' [16,32)B' [32,48)C' [48,64)D'   (all *log2e, D' includes be1)
//  [64,320) wB frags (4 uints/lane)  [320,1344) wC frags (16 uints/lane)
//  [1344,1360) be2*log2e  [1360,1424) bc1*log2e  [1424,1488) Wc2*ln2
template <bool DO_HEAD>
__global__ __launch_bounds__(256) void egnn_layer(
    const float* __restrict__ t,
    const float* __restrict__ coors_in,
    const float* __restrict__ vel_in,
    const float* __restrict__ We1, const float* __restrict__ be1,
    const float* __restrict__ We2, const float* __restrict__ be2,
    const float* __restrict__ Wc1, const float* __restrict__ bc1,
    const float* __restrict__ Wc2, const float* __restrict__ bc2,
    const float* __restrict__ Wv,  const float* __restrict__ bv,
    const float* __restrict__ Wconv1, const float* __restrict__ bconv1,
    const float* __restrict__ Wconv2, const float* __restrict__ bconv2,
    int layer,
    float* __restrict__ coors_out, float* __restrict__ vel_out,
    float* __restrict__ out)
{
    __shared__ float P[1536];

    // ---- per-block prep into LDS (one wave) ----
    if (threadIdx.x < 64) {
        const int pl = threadIdx.x;
        const int pq = pl >> 4, pem = pl & 15;
        const float* We1l = We1 + layer * 128;
        const float* be1l = be1 + layer * 16;
        const float* We2l = We2 + layer * 256;
        const float* be2l = be2 + layer * 16;
        const float* Wc1l = Wc1 + layer * 1024;
        const float* bc1l = bc1 + layer * 64;
        const float* Wc2l = Wc2 + layer * 64;

        if (pl < 16) {
            P[pl]      = (We1l[pl] + We1l[16 + pl] + We1l[32 + pl]) * LOG2E;
            P[16 + pl] = (We1l[48 + pl] + We1l[64 + pl] + We1l[80 + pl]) * LOG2E;
            P[32 + pl] = We1l[96 + pl] * LOG2E;
            P[48 + pl] = (We1l[112 + pl] + be1l[pl]) * LOG2E;
            P[1344 + pl] = be2l[pl] * LOG2E;
        }
        P[1360 + pl] = bc1l[pl] * LOG2E;
        P[1424 + pl] = Wc2l[pl] * LN2f;

        // wB: A[m=pem][k=pq*8+j], k<16 -> hi(We2[k][m]), else lo(We2[k-16][m])
        {
            unsigned wb[4];
#pragma unroll
            for (int d = 0; d < 4; ++d) {
                unsigned short sv[2];
#pragma unroll
                for (int e = 0; e < 2; ++e) {
                    int k = pq * 8 + 2 * d + e;
                    float w = We2l[(k & 15) * 16 + pem];
                    unsigned short hv = f2bf(w);
                    unsigned short lv = f2bf(w - bf2f(hv));
                    sv[e] = (k < 16) ? hv : lv;
                }
                wb[d] = (unsigned)sv[0] | ((unsigned)sv[1] << 16);
            }
            *(uint4*)((unsigned*)(P + 64) + pl * 4) = make_uint4(wb[0], wb[1], wb[2], wb[3]);
        }
        // wC: 4 fragments of 16 out-channels each
#pragma unroll
        for (int f = 0; f < 4; ++f) {
            unsigned wc[4];
#pragma unroll
            for (int d = 0; d < 4; ++d) {
                unsigned short sv[2];
#pragma unroll
                for (int e = 0; e < 2; ++e) {
                    int k = pq * 8 + 2 * d + e;
                    float w = Wc1l[(k & 15) * 64 + 16 * f + pem];
                    unsigned short hv = f2bf(w);
                    unsigned short lv = f2bf(w - bf2f(hv));
                    sv[e] = (k < 16) ? hv : lv;
                }
                wc[d] = (unsigned)sv[0] | ((unsigned)sv[1] << 16);
            }
            *(uint4*)((unsigned*)(P + 320) + pl * 16 + f * 4) = make_uint4(wc[0], wc[1], wc[2], wc[3]);
        }
    }
    __syncthreads();

    const int l   = threadIdx.x & 63;
    const int wvi = threadIdx.x >> 6;
    const int row = blockIdx.x * 4 + wvi;     // b*128 + i
    const int b   = row >> 7;
    const int i   = row & 127;
    const int q   = l >> 4;                   // quad 0..3
    const int em  = l & 15;                   // edge-in-tile / out-row group

    // per-lane fragment loads from LDS
    const float4 a4 = *(const float4*)(P + 0  + q * 4);
    const float4 b4 = *(const float4*)(P + 16 + q * 4);
    const float4 c4 = *(const float4*)(P + 32 + q * 4);
    const float4 d4 = *(const float4*)(P + 48 + q * 4);
    const short8 wB = __builtin_bit_cast(short8, *(const uint4*)((const unsigned*)(P + 64) + l * 4));
    short8 wC[4];
    floatx4 biasC[4];
    float4 w2[4];
#pragma unroll
    for (int f = 0; f < 4; ++f) {
        wC[f] = __builtin_bit_cast(short8, *(const uint4*)((const unsigned*)(P + 320) + l * 16 + f * 4));
        biasC[f] = __builtin_bit_cast(floatx4, *(const float4*)(P + 1360 + f * 16 + q * 4));
        w2[f]    = *(const float4*)(P + 1424 + f * 16 + q * 4);
    }
    const floatx4 biasB = __builtin_bit_cast(floatx4, *(const float4*)(P + 1344 + q * 4));
    const float bc2q = (q == 0) ? bc2[layer] : 0.0f;
    const float wv_s = Wv[layer * 3 + 0] + Wv[layer * 3 + 1] + Wv[layer * 3 + 2];
    const float bvl  = bv[layer];

    const float* tptr = t + b * NN;
    const float ti = tptr[i];
    const float2* cin = (const float2*)coors_in + b * NN;
    const float2 ci = cin[i];

    // shuffle sources for C-layout -> B-operand transform (loop-invariant)
    const int sA = em + ((q & 1) << 5);
    const int sB = sA + 16;

    float ax = 0.0f, ay = 0.0f;

    // rotated tile order: desync trans/VALU phases across waves & blocks
    const int t0 = ((blockIdx.x << 2) + wvi) & 7;

    // prefetch first tile
    float tj_n = tptr[t0 * 16 + em];
    float2 cj_n = cin[t0 * 16 + em];

#pragma unroll 1
    for (int tt2 = 0; tt2 < 8; ++tt2) {
        const float tj = tj_n;
        const float2 cj = cj_n;
        if (tt2 < 7) {                // prefetch next tile (L1/L2-hot)
            const int jn = (((tt2 + 1 + t0) & 7) << 4) + em;
            tj_n = tptr[jn];
            cj_n = cin[jn];
        }
        const float rx = ci.x - cj.x, ry = ci.y - cj.y;
        const float dist = fmaf(rx, rx, ry * ry);

        // Stage A: fp32, result in C-layout (rows 4q+r, col em), *log2e
        float s0 = fmaf(ti, a4.x, fmaf(tj, b4.x, fmaf(dist, c4.x, d4.x)));
        float s1 = fmaf(ti, a4.y, fmaf(tj, b4.y, fmaf(dist, c4.y, d4.y)));
        float s2 = fmaf(ti, a4.z, fmaf(tj, b4.z, fmaf(dist, c4.z, d4.z)));
        float s3 = fmaf(ti, a4.w, fmaf(tj, b4.w, fmaf(dist, c4.w, d4.w)));
        unsigned P0 = packbf(silu_s(s0), silu_s(s1));
        unsigned P1 = packbf(silu_s(s2), silu_s(s3));
        uint4 tb;
        tb.x = (unsigned)__shfl((int)P0, sA, 64);
        tb.y = (unsigned)__shfl((int)P1, sA, 64);
        tb.z = (unsigned)__shfl((int)P0, sB, 64);
        tb.w = (unsigned)__shfl((int)P1, sB, 64);

        // Stage B: m = silu(W2 . e1 + b2); sm = silu(m)
        floatx4 accB = __builtin_amdgcn_mfma_f32_16x16x32_bf16(
            wB, __builtin_bit_cast(short8, tb), biasB, 0, 0, 0);
        unsigned Q0 = packbf(silu_s(silu_s(accB[0])), silu_s(silu_s(accB[1])));
        unsigned Q1 = packbf(silu_s(silu_s(accB[2])), silu_s(silu_s(accB[3])));
        uint4 tc;
        tc.x = (unsigned)__shfl((int)Q0, sA, 64);
        tc.y = (unsigned)__shfl((int)Q1, sA, 64);
        tc.z = (unsigned)__shfl((int)Q0, sB, 64);
        tc.w = (unsigned)__shfl((int)Q1, sB, 64);
        const short8 bC = __builtin_bit_cast(short8, tc);

        // Stage C: h = silu(Wc1 . sm + bc1), 64 channels in 4 fragments
        floatx4 h0 = __builtin_amdgcn_mfma_f32_16x16x32_bf16(wC[0], bC, biasC[0], 0, 0, 0);
        floatx4 h1 = __builtin_amdgcn_mfma_f32_16x16x32_bf16(wC[1], bC, biasC[1], 0, 0, 0);
        floatx4 h2 = __builtin_amdgcn_mfma_f32_16x16x32_bf16(wC[2], bC, biasC[2], 0, 0, 0);
        floatx4 h3 = __builtin_amdgcn_mfma_f32_16x16x32_bf16(wC[3], bC, biasC[3], 0, 0, 0);

        // Stage D: per-lane partial of w_ij over 16 of 64 channels (w2 in regs)
        float wp = bc2q;
#pragma unroll
        for (int r = 0; r < 4; ++r) wp = fmaf(silu_s(h0[r]), ((const float*)&w2[0])[r], wp);
#pragma unroll
        for (int r = 0; r < 4; ++r) wp = fmaf(silu_s(h1[r]), ((const float*)&w2[1])[r], wp);
#pragma unroll
        for (int r = 0; r < 4; ++r) wp = fmaf(silu_s(h2[r]), ((const float*)&w2[2])[r], wp);
#pragma unroll
        for (int r = 0; r < 4; ++r) wp = fmaf(silu_s(h3[r]), ((const float*)&w2[3])[r], wp);

        ax = fmaf(wp, rx, ax);
        ay = fmaf(wp, ry, ay);
    }

    // sum agg over all 64 lanes (quads hold channel-partials, em holds edges)
#pragma unroll
    for (int m = 32; m >= 1; m >>= 1) {
        ax += __shfl_xor(ax, m, 64);
        ay += __shfl_xor(ay, m, 64);
    }

    // node update, computed uniformly on all lanes (ax/ay now uniform)
    const float2 vi2 = ((const float2*)vel_in + b * NN)[i];
    const float phi = fmaf(ti, wv_s, bvl);
    float vx = fmaf(phi, vi2.x, ax);
    float vy = fmaf(phi, vi2.y, ay);
    float cx = selu_f(ci.x + vx);
    float cy = selu_f(ci.y + vy);
    vx = selu_f(vx); vy = selu_f(vy);

    if (!DO_HEAD) {
        if (l == 0) {
            ((float2*)coors_out + b * NN)[i] = make_float2(cx, cy);
            ((float2*)vel_out + b * NN)[i]   = make_float2(vx, vy);
        }
    } else {
        // conv head distributed: channel c = lane&31, butterfly-reduce 4 outs
        const float x0 = selu_f(cx), x1 = selu_f(cy);
        const float x2 = selu_f(vx), x3 = selu_f(vy);
        const int c = l & 31;
        const float4 w1 = *(const float4*)(Wconv1 + c * 4);
        const float xc = selu_f(bconv1[c] + fmaf(x0, w1.x, fmaf(x1, w1.y, fmaf(x2, w1.z, x3 * w1.w))));
        float y0 = xc * Wconv2[c];
        float y1 = xc * Wconv2[32 + c];
        float y2 = xc * Wconv2[64 + c];
        float y3 = xc * Wconv2[96 + c];
#pragma unroll
        for (int m = 16; m >= 1; m >>= 1) {
            y0 += __shfl_xor(y0, m, 64);
            y1 += __shfl_xor(y1, m, 64);
            y2 += __shfl_xor(y2, m, 64);
            y3 += __shfl_xor(y3, m, 64);
        }
        if (l == 0) {
            const int idx = (b * NN + i) * 2;
            *(float2*)(out + idx) = make_float2(y0 + bconv2[0], y1 + bconv2[1]);
            *(float2*)(out + NB * NN * 2 + idx) = make_float2(y2 + bconv2[2], y3 + bconv2[3]);
        }
    }
}

extern "C" void kernel_launch(void* const* d_in, const int* in_sizes, int n_in,
                              void* d_out, int out_size, void* d_ws, size_t ws_size,
                              hipStream_t stream) {
    const float* t      = (const float*)d_in[0];
    const float* coors  = (const float*)d_in[1];
    const float* vel    = (const float*)d_in[2];
    const float* We1    = (const float*)d_in[3];
    const float* be1    = (const float*)d_in[4];
    const float* We2    = (const float*)d_in[5];
    const float* be2    = (const float*)d_in[6];
    const float* Wc1    = (const float*)d_in[7];
    const float* bc1    = (const float*)d_in[8];
    const float* Wc2    = (const float*)d_in[9];
    const float* bc2    = (const float*)d_in[10];
    const float* Wv     = (const float*)d_in[11];
    const float* bv     = (const float*)d_in[12];
    const float* Wconv1 = (const float*)d_in[13];
    const float* bconv1 = (const float*)d_in[14];
    const float* Wconv2 = (const float*)d_in[15];
    const float* bconv2 = (const float*)d_in[16];
    float* out = (float*)d_out;

    float* ws     = (float*)d_ws;
    float* coors1 = ws;                     // B*N*2 floats
    float* vel1   = ws + NB * NN * 2;       // B*N*2 floats

    const dim3 grid(2048), block(256);      // 8192 rows, 1 wave per row

    egnn_layer<false><<<grid, block, 0, stream>>>(
        t, coors, vel, We1, be1, We2, be2, Wc1, bc1, Wc2, bc2, Wv, bv,
        Wconv1, bconv1, Wconv2, bconv2, 0, coors1, vel1, nullptr);

    egnn_layer<true><<<grid, block, 0, stream>>>(
        t, coors1, vel1, We1, be1, We2, be2, Wc1, bc1, Wc2, bc2, Wv, bv,
        Wconv1, bconv1, Wconv2, bconv2, 1, nullptr, nullptr, out);
}

// Round 9
// 156.683 us; speedup vs baseline: 2.0302x; 1.0053x over previous
//
#include <hip/hip_runtime.h>

// EGNN, MFMA core + scale-folded SiLU, 2 dispatches (prep fused into each
// layer kernel as per-block LDS prep). B=64, N=128, M=16, L=2.
// Per wave: one (b,i) row, 8 sequential tiles of 16 edges (+1-tile prefetch).
//  Stage A (collapsed to ti/tj/dist): fp32 VALU in MFMA C-layout.
//  Stage B (16->16), C (16->64): mfma_f32_16x16x32_bf16, weights=A operand,
//    [hi;lo] bf16 split in K=32 slots (~16-bit weight precision).
//  Stage D (64->1): fp32 dot with w2 held in VGPRs + wave butterfly reduce.
// SiLU scale-folding: silu inputs carry log2(e); silu' = x'*rcp(1+exp2(-x'));
// factor absorbed downstream (ln2*log2e=1 -> We2/Wc1 unscaled, biases *log2e,
// Wc2 *ln2). Exact in fp32.
// Session notes:
//  r5: __launch_bounds__(256,8) -> 32 VGPR -> 300MB spill traffic, 3x slow.
//  r6: hipLaunchCooperativeKernel failed silently (co-residency precondition).
//  r7: wall overhead (~70us) is fixed harness cost, not per-dispatch gaps.
//  r8: rotated tile order regressed 42.4->48.2us (convoy theory falsified);
//      stage-D weights from LDS added conflicts+lgkm stalls (keep in VGPRs).

#define NB 64
#define NN 128
#define LOG2E 1.4426950408889634f
#define LN2f  0.6931471805599453f

typedef __attribute__((ext_vector_type(8))) short short8;
typedef __attribute__((ext_vector_type(4))) float floatx4;

__device__ __forceinline__ unsigned short f2bf(float x) {
    unsigned u = __float_as_uint(x);
    return (unsigned short)((u + 0x7FFFu + ((u >> 16) & 1u)) >> 16);
}
__device__ __forceinline__ float bf2f(unsigned short b) {
    return __uint_as_float(((unsigned)b) << 16);
}
// pack two f32 -> bf16x2 (round-half-up): 2 adds + 1 v_perm
__device__ __forceinline__ unsigned packbf(float x, float y) {
    unsigned xb = __float_as_uint(x) + 0x8000u;
    unsigned yb = __float_as_uint(y) + 0x8000u;
    return __builtin_amdgcn_perm(yb, xb, 0x07060302u);
}
// input xs = x*log2e; returns silu(x)*log2e
__device__ __forceinline__ float silu_s(float xs) {
    float e = __builtin_amdgcn_exp2f(-xs);
    return xs * __builtin_amdgcn_rcpf(1.0f + e);
}
__device__ __forceinline__ float selu_f(float x) {
    const float alpha = 1.6732632423543772f;
    const float scale = 1.0507009873554805f;
    float neg = alpha * (__expf(x) - 1.0f);
    return scale * (x > 0.0f ? x : neg);
}

// LDS layout (1536 floats = 6 KB):
//  [0,16)A' [16,32)B' [32,48)C' [48,64)D'   (all *log2e, D' includes be1)
//  [64,320) wB frags (4 uints/lane)  [320,1344) wC frags (16 uints/lane)
//  [1344,1360) be2*log2e  [1360,1424) bc1*log2e  [1424,1488) Wc2*ln2
template <bool DO_HEAD>
__global__ __launch_bounds__(256) void egnn_layer(
    const float* __restrict__ t,
    const float* __restrict__ coors_in,
    const float* __restrict__ vel_in,
    const float* __restrict__ We1, const float* __restrict__ be1,
    const float* __restrict__ We2, const float* __restrict__ be2,
    const float* __restrict__ Wc1, const float* __restrict__ bc1,
    const float* __restrict__ Wc2, const float* __restrict__ bc2,
    const float* __restrict__ Wv,  const float* __restrict__ bv,
    const float* __restrict__ Wconv1, const float* __restrict__ bconv1,
    const float* __restrict__ Wconv2, const float* __restrict__ bconv2,
    int layer,
    float* __restrict__ coors_out, float* __restrict__ vel_out,
    float* __restrict__ out)
{
    __shared__ float P[1536];

    // ---- per-block prep into LDS (one wave) ----
    if (threadIdx.x < 64) {
        const int pl = threadIdx.x;
        const int pq = pl >> 4, pem = pl & 15;
        const float* We1l = We1 + layer * 128;
        const float* be1l = be1 + layer * 16;
        const float* We2l = We2 + layer * 256;
        const float* be2l = be2 + layer * 16;
        const float* Wc1l = Wc1 + layer * 1024;
        const float* bc1l = bc1 + layer * 64;
        const float* Wc2l = Wc2 + layer * 64;

        if (pl < 16) {
            P[pl]      = (We1l[pl] + We1l[16 + pl] + We1l[32 + pl]) * LOG2E;
            P[16 + pl] = (We1l[48 + pl] + We1l[64 + pl] + We1l[80 + pl]) * LOG2E;
            P[32 + pl] = We1l[96 + pl] * LOG2E;
            P[48 + pl] = (We1l[112 + pl] + be1l[pl]) * LOG2E;
            P[1344 + pl] = be2l[pl] * LOG2E;
        }
        P[1360 + pl] = bc1l[pl] * LOG2E;
        P[1424 + pl] = Wc2l[pl] * LN2f;

        // wB: A[m=pem][k=pq*8+j], k<16 -> hi(We2[k][m]), else lo(We2[k-16][m])
        {
            unsigned wb[4];
#pragma unroll
            for (int d = 0; d < 4; ++d) {
                unsigned short sv[2];
#pragma unroll
                for (int e = 0; e < 2; ++e) {
                    int k = pq * 8 + 2 * d + e;
                    float w = We2l[(k & 15) * 16 + pem];
                    unsigned short hv = f2bf(w);
                    unsigned short lv = f2bf(w - bf2f(hv));
                    sv[e] = (k < 16) ? hv : lv;
                }
                wb[d] = (unsigned)sv[0] | ((unsigned)sv[1] << 16);
            }
            *(uint4*)((unsigned*)(P + 64) + pl * 4) = make_uint4(wb[0], wb[1], wb[2], wb[3]);
        }
        // wC: 4 fragments of 16 out-channels each
#pragma unroll
        for (int f = 0; f < 4; ++f) {
            unsigned wc[4];
#pragma unroll
            for (int d = 0; d < 4; ++d) {
                unsigned short sv[2];
#pragma unroll
                for (int e = 0; e < 2; ++e) {
                    int k = pq * 8 + 2 * d + e;
                    float w = Wc1l[(k & 15) * 64 + 16 * f + pem];
                    unsigned short hv = f2bf(w);
                    unsigned short lv = f2bf(w - bf2f(hv));
                    sv[e] = (k < 16) ? hv : lv;
                }
                wc[d] = (unsigned)sv[0] | ((unsigned)sv[1] << 16);
            }
            *(uint4*)((unsigned*)(P + 320) + pl * 16 + f * 4) = make_uint4(wc[0], wc[1], wc[2], wc[3]);
        }
    }
    __syncthreads();

    const int l   = threadIdx.x & 63;
    const int wvi = threadIdx.x >> 6;
    const int row = blockIdx.x * 4 + wvi;     // b*128 + i
    const int b   = row >> 7;
    const int i   = row & 127;
    const int q   = l >> 4;                   // quad 0..3
    const int em  = l & 15;                   // edge-in-tile / out-row group

    // per-lane fragment loads from LDS
    const float4 a4 = *(const float4*)(P + 0  + q * 4);
    const float4 b4 = *(const float4*)(P + 16 + q * 4);
    const float4 c4 = *(const float4*)(P + 32 + q * 4);
    const float4 d4 = *(const float4*)(P + 48 + q * 4);
    const short8 wB = __builtin_bit_cast(short8, *(const uint4*)((const unsigned*)(P + 64) + l * 4));
    short8 wC[4];
    floatx4 biasC[4];
    float4 w2[4];
#pragma unroll
    for (int f = 0; f < 4; ++f) {
        wC[f] = __builtin_bit_cast(short8, *(const uint4*)((const unsigned*)(P + 320) + l * 16 + f * 4));
        biasC[f] = __builtin_bit_cast(floatx4, *(const float4*)(P + 1360 + f * 16 + q * 4));
        w2[f]    = *(const float4*)(P + 1424 + f * 16 + q * 4);
    }
    const floatx4 biasB = __builtin_bit_cast(floatx4, *(const float4*)(P + 1344 + q * 4));
    const float bc2q = (q == 0) ? bc2[layer] : 0.0f;
    const float wv_s = Wv[layer * 3 + 0] + Wv[layer * 3 + 1] + Wv[layer * 3 + 2];
    const float bvl  = bv[layer];

    const float* tptr = t + b * NN;
    const float ti = tptr[i];
    const float2* cin = (const float2*)coors_in + b * NN;
    const float2 ci = cin[i];

    // shuffle sources for C-layout -> B-operand transform (loop-invariant)
    const int sA = em + ((q & 1) << 5);
    const int sB = sA + 16;

    float ax = 0.0f, ay = 0.0f;

    // prefetch tile 0
    float tj_n = tptr[em];
    float2 cj_n = cin[em];

#pragma unroll 1
    for (int tt = 0; tt < 8; ++tt) {
        const float tj = tj_n;
        const float2 cj = cj_n;
        if (tt < 7) {                 // prefetch next tile (L1/L2-hot)
            const int jn = (tt + 1) * 16 + em;
            tj_n = tptr[jn];
            cj_n = cin[jn];
        }
        const float rx = ci.x - cj.x, ry = ci.y - cj.y;
        const float dist = fmaf(rx, rx, ry * ry);

        // Stage A: fp32, result in C-layout (rows 4q+r, col em), *log2e
        float s0 = fmaf(ti, a4.x, fmaf(tj, b4.x, fmaf(dist, c4.x, d4.x)));
        float s1 = fmaf(ti, a4.y, fmaf(tj, b4.y, fmaf(dist, c4.y, d4.y)));
        float s2 = fmaf(ti, a4.z, fmaf(tj, b4.z, fmaf(dist, c4.z, d4.z)));
        float s3 = fmaf(ti, a4.w, fmaf(tj, b4.w, fmaf(dist, c4.w, d4.w)));
        unsigned P0 = packbf(silu_s(s0), silu_s(s1));
        unsigned P1 = packbf(silu_s(s2), silu_s(s3));
        uint4 tb;
        tb.x = (unsigned)__shfl((int)P0, sA, 64);
        tb.y = (unsigned)__shfl((int)P1, sA, 64);
        tb.z = (unsigned)__shfl((int)P0, sB, 64);
        tb.w = (unsigned)__shfl((int)P1, sB, 64);

        // Stage B: m = silu(W2 . e1 + b2); sm = silu(m)
        floatx4 accB = __builtin_amdgcn_mfma_f32_16x16x32_bf16(
            wB, __builtin_bit_cast(short8, tb), biasB, 0, 0, 0);
        unsigned Q0 = packbf(silu_s(silu_s(accB[0])), silu_s(silu_s(accB[1])));
        unsigned Q1 = packbf(silu_s(silu_s(accB[2])), silu_s(silu_s(accB[3])));
        uint4 tc;
        tc.x = (unsigned)__shfl((int)Q0, sA, 64);
        tc.y = (unsigned)__shfl((int)Q1, sA, 64);
        tc.z = (unsigned)__shfl((int)Q0, sB, 64);
        tc.w = (unsigned)__shfl((int)Q1, sB, 64);
        const short8 bC = __builtin_bit_cast(short8, tc);

        // Stage C: h = silu(Wc1 . sm + bc1), 64 channels in 4 fragments
        floatx4 h0 = __builtin_amdgcn_mfma_f32_16x16x32_bf16(wC[0], bC, biasC[0], 0, 0, 0);
        floatx4 h1 = __builtin_amdgcn_mfma_f32_16x16x32_bf16(wC[1], bC, biasC[1], 0, 0, 0);
        floatx4 h2 = __builtin_amdgcn_mfma_f32_16x16x32_bf16(wC[2], bC, biasC[2], 0, 0, 0);
        floatx4 h3 = __builtin_amdgcn_mfma_f32_16x16x32_bf16(wC[3], bC, biasC[3], 0, 0, 0);

        // Stage D: per-lane partial of w_ij over 16 of 64 channels (w2 in regs)
        float wp = bc2q;
#pragma unroll
        for (int r = 0; r < 4; ++r) wp = fmaf(silu_s(h0[r]), ((const float*)&w2[0])[r], wp);
#pragma unroll
        for (int r = 0; r < 4; ++r) wp = fmaf(silu_s(h1[r]), ((const float*)&w2[1])[r], wp);
#pragma unroll
        for (int r = 0; r < 4; ++r) wp = fmaf(silu_s(h2[r]), ((const float*)&w2[2])[r], wp);
#pragma unroll
        for (int r = 0; r < 4; ++r) wp = fmaf(silu_s(h3[r]), ((const float*)&w2[3])[r], wp);

        ax = fmaf(wp, rx, ax);
        ay = fmaf(wp, ry, ay);
    }

    // sum agg over all 64 lanes (quads hold channel-partials, em holds edges)
#pragma unroll
    for (int m = 32; m >= 1; m >>= 1) {
        ax += __shfl_xor(ax, m, 64);
        ay += __shfl_xor(ay, m, 64);
    }

    // node update, computed uniformly on all lanes (ax/ay now uniform)
    const float2 vi2 = ((const float2*)vel_in + b * NN)[i];
    const float phi = fmaf(ti, wv_s, bvl);
    float vx = fmaf(phi, vi2.x, ax);
    float vy = fmaf(phi, vi2.y, ay);
    float cx = selu_f(ci.x + vx);
    float cy = selu_f(ci.y + vy);
    vx = selu_f(vx); vy = selu_f(vy);

    if (!DO_HEAD) {
        if (l == 0) {
            ((float2*)coors_out + b * NN)[i] = make_float2(cx, cy);
            ((float2*)vel_out + b * NN)[i]   = make_float2(vx, vy);
        }
    } else {
        // conv head distributed: channel c = lane&31, butterfly-reduce 4 outs
        const float x0 = selu_f(cx), x1 = selu_f(cy);
        const float x2 = selu_f(vx), x3 = selu_f(vy);
        const int c = l & 31;
        const float4 w1 = *(const float4*)(Wconv1 + c * 4);
        const float xc = selu_f(bconv1[c] + fmaf(x0, w1.x, fmaf(x1, w1.y, fmaf(x2, w1.z, x3 * w1.w))));
        float y0 = xc * Wconv2[c];
        float y1 = xc * Wconv2[32 + c];
        float y2 = xc * Wconv2[64 + c];
        float y3 = xc * Wconv2[96 + c];
#pragma unroll
        for (int m = 16; m >= 1; m >>= 1) {
            y0 += __shfl_xor(y0, m, 64);
            y1 += __shfl_xor(y1, m, 64);
            y2 += __shfl_xor(y2, m, 64);
            y3 += __shfl_xor(y3, m, 64);
        }
        if (l == 0) {
            const int idx = (b * NN + i) * 2;
            *(float2*)(out + idx) = make_float2(y0 + bconv2[0], y1 + bconv2[1]);
            *(float2*)(out + NB * NN * 2 + idx) = make_float2(y2 + bconv2[2], y3 + bconv2[3]);
        }
    }
}

extern "C" void kernel_launch(void* const* d_in, const int* in_sizes, int n_in,
                              void* d_out, int out_size, void* d_ws, size_t ws_size,
                              hipStream_t stream) {
    const float* t      = (const float*)d_in[0];
    const float* coors  = (const float*)d_in[1];
    const float* vel    = (const float*)d_in[2];
    const float* We1    = (const float*)d_in[3];
    const float* be1    = (const float*)d_in[4];
    const float* We2    = (const float*)d_in[5];
    const float* be2    = (const float*)d_in[6];
    const float* Wc1    = (const float*)d_in[7];
    const float* bc1    = (const float*)d_in[8];
    const float* Wc2    = (const float*)d_in[9];
    const float* bc2    = (const float*)d_in[10];
    const float* Wv     = (const float*)d_in[11];
    const float* bv     = (const float*)d_in[12];
    const float* Wconv1 = (const float*)d_in[13];
    const float* bconv1 = (const float*)d_in[14];
    const float* Wconv2 = (const float*)d_in[15];
    const float* bconv2 = (const float*)d_in[16];
    float* out = (float*)d_out;

    float* ws     = (float*)d_ws;
    float* coors1 = ws;                     // B*N*2 floats
    float* vel1   = ws + NB * NN * 2;       // B*N*2 floats

    const dim3 grid(2048), block(256);      // 8192 rows, 1 wave per row

    egnn_layer<false><<<grid, block, 0, stream>>>(
        t, coors, vel, We1, be1, We2, be2, Wc1, bc1, Wc2, bc2, Wv, bv,
        Wconv1, bconv1, Wconv2, bconv2, 0, coors1, vel1, nullptr);

    egnn_layer<true><<<grid, block, 0, stream>>>(
        t, coors1, vel1, We1, be1, We2, be2, Wc1, bc1, Wc2, bc2, Wv, bv,
        Wconv1, bconv1, Wconv2, bconv2, 1, nullptr, nullptr, out);
}